// Round 9
// baseline (87.555 us; speedup 1.0000x reference)
//
#include <hip/hip_runtime.h>

// Bilateral slicing (HDRNet).
// grid  : [B=8][C=12][D=8][Hg=16][Wg=16] fp32  (logical [B,Hg,Wg,D,C] after ref transpose)
// guide : [B=8][1][H=1024][W=1024] fp32 in [0,1)
// out   : [B=8][C=12][H=1024][W=1024] fp32
//
// R9: block = (yg, c, b) owns out[b][c][yg*16 .. yg*16+16][:] -> one 64 KB
// CONTIGUOUS nt-write run per block (fill-like, vs R7b's scattered 4 KB
// bursts). Whole channel grid (2048 floats) staged once in LDS; y-lerp moves
// in-register. Guide re-read x12 is served by L3 (nt-stores don't evict it).

#define BB 8
#define CC 12
#define DD 8
#define HG 16
#define WG 16
#define HH 1024
#define WW 1024
#define ZP 9                       // padded z-stride
#define XS (ZP)                    // x stride (words)
#define YS (WG * ZP)               // y stride = 144 words
#define ROWS 16

typedef float float4v __attribute__((ext_vector_type(4)));

__global__ __launch_bounds__(256) void slice_kernel(
    const float* __restrict__ grid,
    const float* __restrict__ guide,
    float* __restrict__ out)
{
    __shared__ float S[HG * YS];        // 16*144 = 2304 floats = 9.2 KB

    const int yg  = blockIdx.x;   // 0..63  (fastest -> y-interleaved XCD map, like R5)
    const int c   = blockIdx.y;   // 0..11
    const int b   = blockIdx.z;   // 0..7
    const int tid = threadIdx.x;  // 0..255
    const int y0  = yg * ROWS;

    // ---- stage the whole channel grid [z][ygr][xgr] -> LDS [ygr][xgr][z] ----
    const float* gc = grid + (size_t)(b * CC + c) * (DD * HG * WG);
    #pragma unroll
    for (int k = 0; k < 2; ++k) {
        const int idx = tid + k * 256;      // 0..511
        const int e0  = idx * 4;
        const float4 v = *(const float4*)(gc + e0);
        const float vv[4] = {v.x, v.y, v.z, v.w};
        #pragma unroll
        for (int j = 0; j < 4; ++j) {
            const int e   = e0 + j;
            const int z   = e >> 8;
            const int ygr = (e >> 4) & 15;
            const int xgr = e & 15;
            S[ygr * YS + xgr * XS + z] = vv[j];
        }
    }

    // ---- per-thread x weights (fixed across all 16 rows) ----
    const int x0 = tid * 4;
    int   xoff[4];
    float wx1a[4];
    #pragma unroll
    for (int p = 0; p < 4; ++p) {
        const float gx  = ((float)(x0 + p) + 0.5f) * (1.0f / 64.0f);
        const float tx  = gx - 0.5f;
        const int   xb  = (int)fminf(fmaxf(floorf(tx), 0.0f), (float)(WG - 2));
        wx1a[p] = fminf(fmaxf(tx - (float)xb, 0.0f), 1.0f);
        xoff[p] = xb * XS;
    }

    __syncthreads();

    const float* guider = guide + ((size_t)b * HH + y0) * WW + x0;
    float*       outr   = out + ((size_t)(b * CC + c) * HH + y0) * WW + x0;

    float4 gnext = *(const float4*)(guider);

    for (int r = 0; r < ROWS; ++r) {
        const float4 g4 = gnext;
        if (r < ROWS - 1)
            gnext = *(const float4*)(guider + (size_t)(r + 1) * WW);

        // per-row y weights
        const int   y   = y0 + r;
        const float ty  = ((float)y + 0.5f) * (1.0f / 64.0f) - 0.5f;
        const int   yb  = (int)fminf(fmaxf(floorf(ty), 0.0f), (float)(HG - 2));
        const float wy1 = fminf(fmaxf(ty - (float)yb, 0.0f), 1.0f);
        const float* Sy = S + yb * YS;

        const float gvals[4] = {g4.x, g4.y, g4.z, g4.w};
        float rr[4];
        #pragma unroll
        for (int p = 0; p < 4; ++p) {
            const float gz  = gvals[p] * 8.0f;
            const float tz  = gz - 0.5f;
            const int   zb  = (int)fminf(fmaxf(floorf(tz), 0.0f), (float)(DD - 2));
            const float wz1 = fminf(fmaxf(tz - (float)zb, 0.0f), 1.0f);

            const float* p00 = Sy + xoff[p] + zb;
            // 4 z-pairs (ds_read2), lerp z -> x -> y
            const float v00 = p00[0],        v00b = p00[1];
            const float v01 = p00[XS],       v01b = p00[XS + 1];
            const float v10 = p00[YS],       v10b = p00[YS + 1];
            const float v11 = p00[YS + XS],  v11b = p00[YS + XS + 1];

            const float z00 = v00 + wz1 * (v00b - v00);
            const float z01 = v01 + wz1 * (v01b - v01);
            const float z10 = v10 + wz1 * (v10b - v10);
            const float z11 = v11 + wz1 * (v11b - v11);

            const float x0v = z00 + wx1a[p] * (z01 - z00);
            const float x1v = z10 + wx1a[p] * (z11 - z10);
            rr[p] = x0v + wy1 * (x1v - x0v);
        }
        float4v o4 = { rr[0], rr[1], rr[2], rr[3] };
        __builtin_nontemporal_store(o4, (float4v*)(outr + (size_t)r * WW));
    }
}

extern "C" void kernel_launch(void* const* d_in, const int* in_sizes, int n_in,
                              void* d_out, int out_size, void* d_ws, size_t ws_size,
                              hipStream_t stream) {
    const float* grid  = (const float*)d_in[0];  // 8*12*8*16*16
    const float* guide = (const float*)d_in[1];  // 8*1*1024*1024
    float* out = (float*)d_out;                  // 8*12*1024*1024

    slice_kernel<<<dim3(HH / ROWS, CC, BB), dim3(256), 0, stream>>>(grid, guide, out);
}

// Round 10
// 81.364 us; speedup vs baseline: 1.0761x; 1.0761x over previous
//
#include <hip/hip_runtime.h>

// Bilateral slicing (HDRNet).
// grid  : [B=8][C=12][D=8][Hg=16][Wg=16] fp32  (logical [B,Hg,Wg,D,C] after ref transpose)
// guide : [B=8][1][H=1024][W=1024] fp32 in [0,1)
// out   : [B=8][C=12][H=1024][W=1024] fp32
//
// FINAL (R7b, best of 9 rounds @ 81.9 us = 5.3 TB/s effective, 77% of pure-fill):
//  - grid(1024,8): one block per output row; y-interleaved XCD mapping
//    (batch-contiguous remap tested: WORSE; 64KB-contiguous write runs
//     tested: WORSE; 8-row blocks tested: WORSE)
//  - coalesced grid staging via float4 + shfl_xor y-lerp (scattered-gather
//    staging was the R2 limiter: +9 us)
//  - nontemporal float4 output stores (never re-read; skip L3 churn) + guide
//    load hoisted above staging (latency overlap): +4 us
//  - z-contiguous padded LDS layout: consume-side ds_read2 pairs, ~0 bank
//    conflicts

#define BB 8
#define CC 12
#define DD 8
#define HG 16
#define WG 16
#define HH 1024
#define WW 1024
#define ZP 9                      // padded z-stride (bank-conflict-free staging writes)
#define CSTRIDE (WG * ZP)         // 144 words per channel

typedef float float4v __attribute__((ext_vector_type(4)));

__global__ __launch_bounds__(256) void slice_kernel(
    const float* __restrict__ grid,
    const float* __restrict__ guide,
    float* __restrict__ out)
{
    // y-pre-interpolated grid slice for this row: [c][xg][z], z padded to 9
    __shared__ float S[CC * CSTRIDE];   // 1728 floats = 6.9 KB

    const int y   = blockIdx.x;   // 0..1023
    const int b   = blockIdx.y;   // 0..7
    const int tid = threadIdx.x;  // 0..255

    // ---- guide load FIRST: issue before staging so its latency overlaps ----
    const int x0 = tid * 4;
    const float4 g4 = *(const float4*)(guide + ((size_t)b * HH + y) * WW + x0);

    // ---- y interpolation (block-uniform), clamped-base form ----
    const float gy  = ((float)y + 0.5f) * (1.0f / 64.0f);
    const float ty  = gy - 0.5f;
    const int   yb  = (int)fminf(fmaxf(floorf(ty), 0.0f), (float)(HG - 2));
    const float wy1 = fminf(fmaxf(ty - (float)yb, 0.0f), 1.0f);
    const float wy0 = 1.0f - wy1;

    // ---- coalesced grid staging ----
    const float* gb = grid + (size_t)b * (CC * DD * HG * WG);
    #pragma unroll
    for (int k = 0; k < 3; ++k) {
        const int idx   = tid + k * 256;      // 0..767
        const int chunk = idx >> 3;           // 0..95
        const int lane8 = idx & 7;
        const int c = chunk >> 3;
        const int z = chunk & 7;
        const float4 v = *(const float4*)(gb + (size_t)(c * DD + z) * (HG * WG)
                                          + yb * WG + lane8 * 4);
        const float4 o = make_float4(__shfl_xor(v.x, 4),
                                     __shfl_xor(v.y, 4),
                                     __shfl_xor(v.z, 4),
                                     __shfl_xor(v.w, 4));
        if (lane8 < 4) {   // this lane holds row yb, partner holds yb+1
            const int xg0 = lane8 * 4;
            float* dst = &S[c * CSTRIDE + xg0 * ZP + z];
            dst[0 * ZP] = wy0 * v.x + wy1 * o.x;
            dst[1 * ZP] = wy0 * v.y + wy1 * o.y;
            dst[2 * ZP] = wy0 * v.z + wy1 * o.z;
            dst[3 * ZP] = wy0 * v.w + wy1 * o.w;
        }
    }

    // ---- weights: compute BEFORE the barrier (only needs g4 + x) ----
    const float gvals[4] = {g4.x, g4.y, g4.z, g4.w};
    float w00[4], w01[4], w10[4], w11[4];
    int a0[4];
    #pragma unroll
    for (int p = 0; p < 4; ++p) {
        // z interpolation, clamped-base form
        const float gz  = gvals[p] * 8.0f;
        const float tz  = gz - 0.5f;
        const int   zb  = (int)fminf(fmaxf(floorf(tz), 0.0f), (float)(DD - 2));
        const float wz1 = fminf(fmaxf(tz - (float)zb, 0.0f), 1.0f);
        const float wz0 = 1.0f - wz1;

        // x interpolation, clamped-base form
        const float gx  = ((float)(x0 + p) + 0.5f) * (1.0f / 64.0f);
        const float tx  = gx - 0.5f;
        const int   xb  = (int)fminf(fmaxf(floorf(tx), 0.0f), (float)(WG - 2));
        const float wx1 = fminf(fmaxf(tx - (float)xb, 0.0f), 1.0f);
        const float wx0 = 1.0f - wx1;

        w00[p] = wx0 * wz0;
        w01[p] = wx0 * wz1;
        w10[p] = wx1 * wz0;
        w11[p] = wx1 * wz1;
        a0[p]  = xb * ZP + zb;
    }

    __syncthreads();

    float* outp = out + ((size_t)(b * CC) * HH + y) * WW + x0;

    #pragma unroll
    for (int c = 0; c < CC; ++c) {
        const float* base = S + c * CSTRIDE;
        float r[4];
        #pragma unroll
        for (int p = 0; p < 4; ++p) {
            const float va0 = base[a0[p]];          // (xb,   zb)
            const float va1 = base[a0[p] + 1];      // (xb,   zb+1)
            const float vb0 = base[a0[p] + ZP];     // (xb+1, zb)
            const float vb1 = base[a0[p] + ZP + 1]; // (xb+1, zb+1)
            r[p] = w00[p] * va0 + w01[p] * va1 + w10[p] * vb0 + w11[p] * vb1;
        }
        // nontemporal: output is never re-read — don't churn L2/L3 with it
        float4v o4 = { r[0], r[1], r[2], r[3] };
        __builtin_nontemporal_store(o4, (float4v*)(outp + (size_t)c * (HH * WW)));
    }
}

extern "C" void kernel_launch(void* const* d_in, const int* in_sizes, int n_in,
                              void* d_out, int out_size, void* d_ws, size_t ws_size,
                              hipStream_t stream) {
    const float* grid  = (const float*)d_in[0];  // 8*12*8*16*16
    const float* guide = (const float*)d_in[1];  // 8*1*1024*1024
    float* out = (float*)d_out;                  // 8*12*1024*1024

    slice_kernel<<<dim3(HH, BB), dim3(256), 0, stream>>>(grid, guide, out);
}